// Round 3
// baseline (331.308 us; speedup 1.0000x reference)
//
#include <hip/hip_runtime.h>
#include <math.h>

// HybridFrequencyEncoder: fused Haar DWT (16,3,1024,1024 -> 4x half-res) + 8x8 DCT-II on LL.
// Output: [LL_dct | LH | HL | HH], each (16,3,512,512) fp32, concatenated flat.
//
// Tile: 32 input rows x 256 input cols -> LL tile 16x128 (2x16 grid of 8x8 DCT blocks).
// 256 threads/block, 6144 blocks.
// Phase 1: thread (hr, bcol) loads 2x16 input floats (8x dwordx4), Haar in regs,
//          stores LH/HL/HH (dwordx4), row-pass DCT fully in registers with LITERAL
//          coefficients (64 v_fmac), writes T row-chunk to LDS (2x ds_write_b128).
// Phase 2: thread (orow, bcol) reads 8 T row-chunks (16x ds_read_b128), col-pass DCT
//          with per-thread coefficient row from tiny LDS Dm, stores LL_dct (dwordx4).

#define NOUT ((size_t)48 * 512 * 512)   // elements per subband

#define C0 0.35355339059327376f
#define C1 0.49039264020161522f
#define C2 0.46193976625564337f
#define C3 0.41573480615127262f
#define C4 0.35355339059327376f
#define C5 0.27778511650980111f
#define C6 0.19134171618254489f
#define C7 0.09754516100806414f

#define LD4(dst, src) do { float4 _v = *(const float4*)(src); \
    (dst)[0]=_v.x; (dst)[1]=_v.y; (dst)[2]=_v.z; (dst)[3]=_v.w; } while(0)

__global__ __launch_bounds__(256) void hfe_kernel(const float* __restrict__ x,
                                                  float* __restrict__ out) {
    // DCT-II matrix as compile-time constants (row pass uses these as literals)
    static constexpr float DMc[8][8] = {
        { C0,  C0,  C0,  C0,  C0,  C0,  C0,  C0},
        { C1,  C3,  C5,  C7, -C7, -C5, -C3, -C1},
        { C2,  C6, -C6, -C2, -C2, -C6,  C6,  C2},
        { C3, -C7, -C1, -C5,  C5,  C1,  C7, -C3},
        { C4, -C4, -C4,  C4,  C4, -C4, -C4,  C4},
        { C5, -C1,  C7,  C3, -C3, -C7,  C1, -C5},
        { C6, -C2,  C2, -C6, -C6,  C2, -C2,  C6},
        { C7, -C5,  C3, -C1,  C1, -C3,  C5, -C7},
    };

    __shared__ float4 T4[16][33];   // row-pass result, 132-float row stride (pad)
    __shared__ float  Dm[8][8];     // coefficient rows for col pass (runtime k index)

    const int t = threadIdx.x;

    if (t < 64) {
        const int k = t >> 3, n = t & 7;
        double v = (k == 0) ? 0.35355339059327376220
                            : 0.5 * cos(M_PI * (double)(k * (2 * n + 1)) / 16.0);
        Dm[k][n] = (float)v;
    }

    const int bid = blockIdx.x;
    const int bc  = bid >> 7;          // image 0..47
    const int rem = bid & 127;
    const int ty  = rem >> 2;          // 0..31 : 32-row input tile
    const int tx  = rem & 3;           // 0..3  : 256-col input tile

    const size_t img_in  = (size_t)bc * (1024 * 1024);
    const size_t img_out = (size_t)bc * (512 * 512);

    // ---------------- Phase 1: Haar + row-pass DCT ----------------
    const int hr   = t >> 4;           // 0..15 : LL row within tile
    const int bcol = t & 15;           // 0..15 : 8x8 block column

    const int in_row = ty * 32 + hr * 2;
    const int in_col = tx * 256 + bcol * 16;
    const float* p0 = x + img_in + (size_t)in_row * 1024 + in_col;
    const float* p1 = p0 + 1024;

    float e[16], o[16];
    LD4(&e[0], p0 + 0); LD4(&e[4], p0 + 4); LD4(&e[8], p0 + 8); LD4(&e[12], p0 + 12);
    LD4(&o[0], p1 + 0); LD4(&o[4], p1 + 4); LD4(&o[8], p1 + 8); LD4(&o[12], p1 + 12);

    float ll[8], lh[8], hl[8], hh[8];
#pragma unroll
    for (int n = 0; n < 8; ++n) {
        const float s1 = e[2*n] + e[2*n+1], d1 = e[2*n] - e[2*n+1];
        const float s2 = o[2*n] + o[2*n+1], d2 = o[2*n] - o[2*n+1];
        ll[n] = (s1 + s2) * 0.5f;
        lh[n] = (s1 - s2) * 0.5f;
        hl[n] = (d1 + d2) * 0.5f;
        hh[n] = (d1 - d2) * 0.5f;
    }

    const int h_row = ty * 16 + hr;
    const int h_col = tx * 128 + bcol * 8;
    float* ob = out + img_out + (size_t)h_row * 512 + h_col;
    *(float4*)(ob + NOUT)         = make_float4(lh[0], lh[1], lh[2], lh[3]);
    *(float4*)(ob + NOUT + 4)     = make_float4(lh[4], lh[5], lh[6], lh[7]);
    *(float4*)(ob + 2 * NOUT)     = make_float4(hl[0], hl[1], hl[2], hl[3]);
    *(float4*)(ob + 2 * NOUT + 4) = make_float4(hl[4], hl[5], hl[6], hl[7]);
    *(float4*)(ob + 3 * NOUT)     = make_float4(hh[0], hh[1], hh[2], hh[3]);
    *(float4*)(ob + 3 * NOUT + 4) = make_float4(hh[4], hh[5], hh[6], hh[7]);

    // Row pass: tr[l] = sum_n ll[n] * D[l][n]  (all coefficients literal)
    float tr[8];
#pragma unroll
    for (int l = 0; l < 8; ++l) {
        float acc = ll[0] * DMc[l][0];
#pragma unroll
        for (int n = 1; n < 8; ++n) acc = fmaf(ll[n], DMc[l][n], acc);
        tr[l] = acc;
    }
    T4[hr][bcol * 2]     = make_float4(tr[0], tr[1], tr[2], tr[3]);
    T4[hr][bcol * 2 + 1] = make_float4(tr[4], tr[5], tr[6], tr[7]);

    __syncthreads();

    // ---------------- Phase 2: col-pass DCT ----------------
    const int orow = t >> 4;           // 0..15 : output row within tile
    const int bc2  = t & 15;           // 0..15 : block column
    const int brow = orow >> 3;
    const int k    = orow & 7;

    float Dk[8];
#pragma unroll
    for (int m = 0; m < 8; ++m) Dk[m] = Dm[k][m];

    float4 a0 = make_float4(0.f, 0.f, 0.f, 0.f);
    float4 a1 = a0;
#pragma unroll
    for (int m = 0; m < 8; ++m) {
        const float dk = Dk[m];
        const float4 t0 = T4[brow * 8 + m][bc2 * 2];
        const float4 t1 = T4[brow * 8 + m][bc2 * 2 + 1];
        a0.x = fmaf(dk, t0.x, a0.x); a0.y = fmaf(dk, t0.y, a0.y);
        a0.z = fmaf(dk, t0.z, a0.z); a0.w = fmaf(dk, t0.w, a0.w);
        a1.x = fmaf(dk, t1.x, a1.x); a1.y = fmaf(dk, t1.y, a1.y);
        a1.z = fmaf(dk, t1.z, a1.z); a1.w = fmaf(dk, t1.w, a1.w);
    }

    float* oc = out + img_out + (size_t)(ty * 16 + orow) * 512 + tx * 128 + bc2 * 8;
    *(float4*)(oc)     = a0;
    *(float4*)(oc + 4) = a1;
}

extern "C" void kernel_launch(void* const* d_in, const int* in_sizes, int n_in,
                              void* d_out, int out_size, void* d_ws, size_t ws_size,
                              hipStream_t stream) {
    const float* x = (const float*)d_in[0];
    float* out = (float*)d_out;
    // 48 images * (1024/32 row tiles) * (1024/256 col tiles) = 48*32*4 = 6144 blocks
    hfe_kernel<<<dim3(6144), dim3(256), 0, stream>>>(x, out);
}